// Round 2
// baseline (722.056 us; speedup 1.0000x reference)
//
#include <hip/hip_runtime.h>
#include <stdint.h>

#define B_   4096
#define T_   48
#define D_   35
#define H_   64
#define KROW 168   // LDS A-row stride (elements); MFMA K extent = 160 = 5*32
#define BT   8     // batch rows per block

typedef float f32x4 __attribute__((ext_vector_type(4)));
typedef short bf16x8 __attribute__((ext_vector_type(8)));

__device__ __forceinline__ float sigm(float z)  { return 1.0f / (1.0f + __expf(-z)); }
__device__ __forceinline__ float tanh_(float z) { return 2.0f / (1.0f + __expf(-2.0f * z)) - 1.0f; }
__device__ __forceinline__ unsigned short f2bf(float x) {
    union { float f; uint32_t u; } v; v.f = x;
    return (unsigned short)((v.u + 0x7fffu + ((v.u >> 16) & 1u)) >> 16);
}
__device__ __forceinline__ float bf2f(unsigned short b) {
    union { uint32_t u; float f; } v; v.u = ((uint32_t)b) << 16;
    return v.f;
}

// K-axis layout (shared by A tile and weight fragments):
//   k 0..34  = x_c   -> W_ih[:, 0:35]
//   k 35..69 = m     -> W_ih[:, 35:70]
//   k 70..71 = 0
//   k 72..135= h     -> W_hh
//   k 136..159 = 0

__global__ __launch_bounds__(256, 2)
void brits_main(const float* __restrict__ x_t, const float* __restrict__ masks,
                const float* __restrict__ W_ih, const float* __restrict__ W_hh,
                const float* __restrict__ b_ih, const float* __restrict__ b_hh,
                const float* __restrict__ W_reg, const float* __restrict__ b_reg,
                const float* __restrict__ W_out, const float* __restrict__ b_out,
                float* __restrict__ ws, float* __restrict__ out)
{
    __shared__ unsigned short Abuf[2][16 * KROW]; // rows 8..15 stay zero (BT=8)
    __shared__ float wout[65];

    const int tid    = threadIdx.x;
    const int lane   = tid & 63;
    const int w      = tid >> 6;      // wave 0..3
    const int g      = lane >> 4;     // k-group 0..3 / row-group in C
    const int cc     = lane & 15;
    const int batch0 = blockIdx.x * BT;
    const int u      = w * 16 + cc;   // hidden unit / output column

    for (int i = tid; i < 2 * 16 * KROW; i += 256) ((unsigned short*)Abuf)[i] = 0;
    if (tid < 65) wout[tid] = (tid < 64) ? W_out[tid] : b_out[0];

    // ---- weights -> registers (constant across all 48 steps) ----
    bf16x8 Wf[4][5];   // [gate n-tile][k-chunk]
    #pragma unroll
    for (int nt = 0; nt < 4; ++nt) {
        const int n = nt * 64 + u;
        #pragma unroll
        for (int kk = 0; kk < 5; ++kk) {
            bf16x8 v;
            #pragma unroll
            for (int i = 0; i < 8; ++i) {
                const int k = kk * 32 + 8 * g + i;
                float f = 0.f;
                if (k < 70)                 f = W_ih[n * 70 + k];
                else if (k >= 72 && k < 136) f = W_hh[n * 64 + (k - 72)];
                v[i] = (short)f2bf(f);
            }
            Wf[nt][kk] = v;
        }
    }
    bf16x8 Wr[2];      // W_reg fragments (waves 0..2, u<35; else zero)
    #pragma unroll
    for (int kk = 0; kk < 2; ++kk) {
        bf16x8 v;
        #pragma unroll
        for (int i = 0; i < 8; ++i) {
            const int k = kk * 32 + 8 * g + i;
            float f = (w < 3 && u < 35) ? W_reg[u * 64 + k] : 0.f;
            v[i] = (short)f2bf(f);
        }
        Wr[kk] = v;
    }
    const float brg = (w < 3 && u < 35) ? b_reg[u] : 0.f;
    const float bi  = b_ih[u]       + b_hh[u];
    const float bf_ = b_ih[64 + u]  + b_hh[64 + u];
    const float bg  = b_ih[128 + u] + b_hh[128 + u];
    const float bo  = b_ih[192 + u] + b_hh[192 + u];
    __syncthreads();

    float c_reg[4] = {0.f, 0.f, 0.f, 0.f};
    const bool pl = (w < 3) && (u < 35) && (g < 2);  // P1-epilogue lanes (rows 0..7)
    float xr[4], mr[4];
    if (pl) {
        #pragma unroll
        for (int j = 0; j < 4; ++j) {
            const int gi = ((batch0 + 4 * g + j) * T_ + 0) * D_ + u;
            xr[j] = x_t[gi]; mr[j] = masks[gi];
        }
    }

    for (int t = 0; t < T_; ++t) {
        unsigned short* A  = Abuf[t & 1];
        unsigned short* An = Abuf[(t + 1) & 1];

        // ---- P1: x_hat = h @ W_reg^T + b_reg ----
        if (w < 3) {
            f32x4 acc = {0.f, 0.f, 0.f, 0.f};
            #pragma unroll
            for (int kk = 0; kk < 2; ++kk) {
                bf16x8 a = *(const bf16x8*)&A[cc * KROW + 72 + kk * 32 + 8 * g];
                acc = __builtin_amdgcn_mfma_f32_16x16x32_bf16(a, Wr[kk], acc, 0, 0, 0);
            }
            float lnum = 0.f, lden = 0.f;
            if (u < 35 && g < 2) {
                #pragma unroll
                for (int j = 0; j < 4; ++j) {
                    const int r  = 4 * g + j;
                    const int gi = ((batch0 + r) * T_ + t) * D_ + u;
                    const float xh = acc[j] + brg;
                    const float xc = mr[j] * xr[j] + (1.f - mr[j]) * xh;
                    lnum += fabsf(xr[j] - xh) * mr[j];
                    lden += mr[j];
                    out[1 + B_ + gi]     = xc;          // imputations
                    A[r * KROW + u]      = f2bf(xc);
                    A[r * KROW + 35 + u] = f2bf(mr[j]);
                }
            }
            // per-step loss partials: wave-reduce, one atomic per wave
            #pragma unroll
            for (int off = 1; off < 64; off <<= 1) {
                lnum += __shfl_xor(lnum, off, 64);
                lden += __shfl_xor(lden, off, 64);
            }
            if (lane == 0) {
                atomicAdd(&ws[t],      lnum);
                atomicAdd(&ws[T_ + t], lden);
            }
            // prefetch x,m for t+1 (covered by bar + P2 + P3)
            if (u < 35 && g < 2) {
                const int tn = (t < T_ - 1) ? t + 1 : t;
                #pragma unroll
                for (int j = 0; j < 4; ++j) {
                    const int gi = ((batch0 + 4 * g + j) * T_ + tn) * D_ + u;
                    xr[j] = x_t[gi]; mr[j] = masks[gi];
                }
            }
        }
        __syncthreads();   // x_c/m visible to all waves

        // ---- P2: gates = A @ Wcomb^T (weights in VGPRs) ----
        f32x4 ai = {0,0,0,0}, af = {0,0,0,0}, ag = {0,0,0,0}, ao = {0,0,0,0};
        #pragma unroll
        for (int kk = 0; kk < 5; ++kk) {
            bf16x8 a = *(const bf16x8*)&A[cc * KROW + kk * 32 + 8 * g];
            ai = __builtin_amdgcn_mfma_f32_16x16x32_bf16(a, Wf[0][kk], ai, 0, 0, 0);
            af = __builtin_amdgcn_mfma_f32_16x16x32_bf16(a, Wf[1][kk], af, 0, 0, 0);
            ag = __builtin_amdgcn_mfma_f32_16x16x32_bf16(a, Wf[2][kk], ag, 0, 0, 0);
            ao = __builtin_amdgcn_mfma_f32_16x16x32_bf16(a, Wf[3][kk], ao, 0, 0, 0);
        }

        // ---- P3: cell update, write new h into next buffer ----
        if (g < 2) {
            #pragma unroll
            for (int j = 0; j < 4; ++j) {
                float iv = sigm (ai[j] + bi);
                float fv = sigm (af[j] + bf_);
                float gv = tanh_(ag[j] + bg);
                float ov = sigm (ao[j] + bo);
                float cn = fv * c_reg[j] + iv * gv;
                c_reg[j] = cn;
                An[(4 * g + j) * KROW + 72 + u] = f2bf(ov * tanh_(cn));
            }
        }
        __syncthreads();   // new h visible before next step
    }

    // ---- y_h = sigmoid(h_final @ W_out^T + b_out); final h in Abuf[0] ----
    if (w == 0 && cc < BT) {
        float p = 0.f;
        #pragma unroll
        for (int k = 0; k < 16; ++k)
            p += bf2f(Abuf[0][cc * KROW + 72 + 16 * g + k]) * wout[16 * g + k];
        p += __shfl_xor(p, 16, 64);
        p += __shfl_xor(p, 32, 64);
        if (lane < 16) out[1 + batch0 + cc] = sigm(p + wout[64]);
    }
}

// loss = (1/T) * sum_t num[t] / (den[t] + 1e-5)
__global__ void post_kernel(const float* __restrict__ ws, float* __restrict__ out)
{
    const int t = threadIdx.x;  // 64 threads
    float v = (t < T_) ? ws[t] / (ws[T_ + t] + 1e-5f) : 0.f;
    #pragma unroll
    for (int off = 1; off < 64; off <<= 1) v += __shfl_xor(v, off, 64);
    if (t == 0) out[0] = v * (1.0f / T_);
}

extern "C" void kernel_launch(void* const* d_in, const int* in_sizes, int n_in,
                              void* d_out, int out_size, void* d_ws, size_t ws_size,
                              hipStream_t stream) {
    const float* x_t   = (const float*)d_in[0];
    const float* masks = (const float*)d_in[1];
    const float* W_ih  = (const float*)d_in[6];
    const float* W_hh  = (const float*)d_in[7];
    const float* b_ih  = (const float*)d_in[8];
    const float* b_hh  = (const float*)d_in[9];
    const float* W_reg = (const float*)d_in[10];
    const float* b_reg = (const float*)d_in[11];
    const float* W_out = (const float*)d_in[14];
    const float* b_out = (const float*)d_in[15];
    float* out = (float*)d_out;
    float* ws  = (float*)d_ws;

    hipMemsetAsync(ws, 0, 2 * T_ * sizeof(float), stream);
    brits_main<<<B_ / BT, 256, 0, stream>>>(x_t, masks, W_ih, W_hh, b_ih, b_hh,
                                            W_reg, b_reg, W_out, b_out, ws, out);
    post_kernel<<<1, 64, 0, stream>>>(ws, out);
}

// Round 3
// 147.761 us; speedup vs baseline: 4.8867x; 4.8867x over previous
//
#include <hip/hip_runtime.h>
#include <stdint.h>

#define B_   4096
#define T_   48
#define D_   35
#define H_   64
#define KROW 168   // LDS A-row stride (elements); MFMA K extent = 160 = 5*32
#define BT   8     // batch rows per block

typedef float f32x4 __attribute__((ext_vector_type(4)));
typedef short bf16x8 __attribute__((ext_vector_type(8)));

__device__ __forceinline__ float sigm(float z)  { return 1.0f / (1.0f + __expf(-z)); }
__device__ __forceinline__ float tanh_(float z) { return 2.0f / (1.0f + __expf(-2.0f * z)) - 1.0f; }
__device__ __forceinline__ unsigned short f2bf(float x) {
    union { float f; uint32_t u; } v; v.f = x;
    return (unsigned short)((v.u + 0x7fffu + ((v.u >> 16) & 1u)) >> 16);
}
__device__ __forceinline__ float bf2f(unsigned short b) {
    union { uint32_t u; float f; } v; v.u = ((uint32_t)b) << 16;
    return v.f;
}

// Pre-pass: ws[t] = sum over (b,d) of masks[b][t][d]. 8 atomics per address -> cheap.
// Also zeroes out[0] (loss accumulator).
__global__ void pre_kernel(const float* __restrict__ masks, float* __restrict__ ws,
                           float* __restrict__ out)
{
    const int t     = blockIdx.x % T_;
    const int chunk = blockIdx.x / T_;   // 8 chunks of 512 batch rows
    const int tid   = threadIdx.x;
    if (blockIdx.x == 0 && tid == 0) out[0] = 0.0f;
    float s = 0.f;
    for (int idx = tid; idx < 512 * D_; idx += 256) {
        int b = chunk * 512 + idx / D_;
        int d = idx % D_;
        s += masks[(b * T_ + t) * D_ + d];
    }
    #pragma unroll
    for (int off = 32; off; off >>= 1) s += __shfl_down(s, off, 64);
    __shared__ float red[4];
    if ((tid & 63) == 0) red[tid >> 6] = s;
    __syncthreads();
    if (tid == 0) atomicAdd(&ws[t], red[0] + red[1] + red[2] + red[3]);
}

// K-axis layout (shared by A tile and weight fragments):
//   k 0..34  = x_c -> W_ih[:,0:35] ; k 35..69 = m -> W_ih[:,35:70]
//   k 70..71 = 0   ; k 72..135 = h -> W_hh    ; k 136..159 = 0

__global__ __launch_bounds__(256, 2)
void brits_main(const float* __restrict__ x_t, const float* __restrict__ masks,
                const float* __restrict__ W_ih, const float* __restrict__ W_hh,
                const float* __restrict__ b_ih, const float* __restrict__ b_hh,
                const float* __restrict__ W_reg, const float* __restrict__ b_reg,
                const float* __restrict__ W_out, const float* __restrict__ b_out,
                const float* __restrict__ msum, float* __restrict__ out)
{
    __shared__ unsigned short Abuf[2][16 * KROW]; // rows 8..15 stay zero (BT=8)
    __shared__ float wout[65];
    __shared__ float invms[T_];
    __shared__ float redbuf[4];

    const int tid    = threadIdx.x;
    const int lane   = tid & 63;
    const int w      = tid >> 6;      // wave 0..3
    const int g      = lane >> 4;     // k-group / C row-group
    const int cc     = lane & 15;
    const int batch0 = blockIdx.x * BT;
    const int u      = w * 16 + cc;   // hidden unit / output column

    for (int i = tid; i < 2 * 16 * KROW; i += 256) ((unsigned short*)Abuf)[i] = 0;
    if (tid < 65) wout[tid] = (tid < 64) ? W_out[tid] : b_out[0];
    if (tid < T_) invms[tid] = 1.0f / (msum[tid] + 1e-5f);

    // ---- weights -> registers (constant across all 48 steps) ----
    bf16x8 Wf[4][5];   // [gate n-tile][k-chunk]
    #pragma unroll
    for (int nt = 0; nt < 4; ++nt) {
        const int n = nt * 64 + u;
        #pragma unroll
        for (int kk = 0; kk < 5; ++kk) {
            bf16x8 v;
            #pragma unroll
            for (int i = 0; i < 8; ++i) {
                const int k = kk * 32 + 8 * g + i;
                float f = 0.f;
                if (k < 70)                  f = W_ih[n * 70 + k];
                else if (k >= 72 && k < 136) f = W_hh[n * 64 + (k - 72)];
                v[i] = (short)f2bf(f);
            }
            Wf[nt][kk] = v;
        }
    }
    bf16x8 Wr[2];      // W_reg fragments (waves 0..2, u<35; else zero)
    #pragma unroll
    for (int kk = 0; kk < 2; ++kk) {
        bf16x8 v;
        #pragma unroll
        for (int i = 0; i < 8; ++i) {
            const int k = kk * 32 + 8 * g + i;
            float f = (w < 3 && u < 35) ? W_reg[u * 64 + k] : 0.f;
            v[i] = (short)f2bf(f);
        }
        Wr[kk] = v;
    }
    const float brg = (w < 3 && u < 35) ? b_reg[u] : 0.f;
    const float bi  = b_ih[u]       + b_hh[u];
    const float bf_ = b_ih[64 + u]  + b_hh[64 + u];
    const float bg  = b_ih[128 + u] + b_hh[128 + u];
    const float bo  = b_ih[192 + u] + b_hh[192 + u];
    __syncthreads();

    float c_reg[4] = {0.f, 0.f, 0.f, 0.f};
    float loss_acc = 0.f;
    const bool pl = (w < 3) && (u < 35) && (g < 2);  // P1-epilogue lanes (rows 0..7)
    float xr[4], mr[4], xc[4];
    if (pl) {
        #pragma unroll
        for (int j = 0; j < 4; ++j) {
            const int gi = ((batch0 + 4 * g + j) * T_ + 0) * D_ + u;
            xr[j] = x_t[gi]; mr[j] = masks[gi];
        }
    }

    for (int t = 0; t < T_; ++t) {
        unsigned short* A  = Abuf[t & 1];
        unsigned short* An = Abuf[(t + 1) & 1];

        // ---- P1: x_hat = h @ W_reg^T + b_reg; epilogue -> LDS only ----
        if (w < 3) {
            f32x4 acc = {0.f, 0.f, 0.f, 0.f};
            #pragma unroll
            for (int kk = 0; kk < 2; ++kk) {
                bf16x8 a = *(const bf16x8*)&A[cc * KROW + 72 + kk * 32 + 8 * g];
                acc = __builtin_amdgcn_mfma_f32_16x16x32_bf16(a, Wr[kk], acc, 0, 0, 0);
            }
            if (pl) {
                const float inv = invms[t];
                #pragma unroll
                for (int j = 0; j < 4; ++j) {
                    const int r  = 4 * g + j;
                    const float xh = acc[j] + brg;
                    xc[j] = mr[j] * xr[j] + (1.f - mr[j]) * xh;
                    loss_acc += fabsf(xr[j] - xh) * mr[j] * inv;
                    A[r * KROW + u]      = f2bf(xc[j]);
                    A[r * KROW + 35 + u] = f2bf(mr[j]);
                }
            }
        }
        __syncthreads();   // drains LDS writes; no outstanding global ops here

        // ---- deferred global stores + prefetch (drained at end-of-step barrier,
        //      covered by P2 + P3) ----
        if (pl) {
            #pragma unroll
            for (int j = 0; j < 4; ++j) {
                const int gi = ((batch0 + 4 * g + j) * T_ + t) * D_ + u;
                out[1 + B_ + gi] = xc[j];           // imputations
            }
            const int tn = (t < T_ - 1) ? t + 1 : t;
            #pragma unroll
            for (int j = 0; j < 4; ++j) {
                const int gi = ((batch0 + 4 * g + j) * T_ + tn) * D_ + u;
                xr[j] = x_t[gi]; mr[j] = masks[gi];
            }
        }

        // ---- P2: gates = A @ Wcomb^T (weights in VGPRs) ----
        f32x4 ai = {0,0,0,0}, af = {0,0,0,0}, ag = {0,0,0,0}, ao = {0,0,0,0};
        #pragma unroll
        for (int kk = 0; kk < 5; ++kk) {
            bf16x8 a = *(const bf16x8*)&A[cc * KROW + kk * 32 + 8 * g];
            ai = __builtin_amdgcn_mfma_f32_16x16x32_bf16(a, Wf[0][kk], ai, 0, 0, 0);
            af = __builtin_amdgcn_mfma_f32_16x16x32_bf16(a, Wf[1][kk], af, 0, 0, 0);
            ag = __builtin_amdgcn_mfma_f32_16x16x32_bf16(a, Wf[2][kk], ag, 0, 0, 0);
            ao = __builtin_amdgcn_mfma_f32_16x16x32_bf16(a, Wf[3][kk], ao, 0, 0, 0);
        }

        // ---- P3: cell update, write new h into next buffer ----
        if (g < 2) {
            #pragma unroll
            for (int j = 0; j < 4; ++j) {
                float iv = sigm (ai[j] + bi);
                float fv = sigm (af[j] + bf_);
                float gv = tanh_(ag[j] + bg);
                float ov = sigm (ao[j] + bo);
                float cn = fv * c_reg[j] + iv * gv;
                c_reg[j] = cn;
                An[(4 * g + j) * KROW + 72 + u] = f2bf(ov * tanh_(cn));
            }
        }
        __syncthreads();   // new h visible; drains imputation stores + prefetch
    }

    // ---- loss reduction: one atomic per block ----
    float v = loss_acc;
    #pragma unroll
    for (int off = 32; off; off >>= 1) v += __shfl_down(v, off, 64);
    if ((tid & 63) == 0) redbuf[w] = v;
    __syncthreads();
    if (tid == 0) atomicAdd(out, (redbuf[0] + redbuf[1] + redbuf[2] + redbuf[3]) * (1.0f / T_));

    // ---- y_h = sigmoid(h_final @ W_out^T + b_out); final h in Abuf[0] ----
    if (w == 0 && cc < BT) {
        float p = 0.f;
        #pragma unroll
        for (int k = 0; k < 16; ++k)
            p += bf2f(Abuf[0][cc * KROW + 72 + 16 * g + k]) * wout[16 * g + k];
        p += __shfl_xor(p, 16, 64);
        p += __shfl_xor(p, 32, 64);
        if (lane < 16) out[1 + batch0 + cc] = sigm(p + wout[64]);
    }
}

extern "C" void kernel_launch(void* const* d_in, const int* in_sizes, int n_in,
                              void* d_out, int out_size, void* d_ws, size_t ws_size,
                              hipStream_t stream) {
    const float* x_t   = (const float*)d_in[0];
    const float* masks = (const float*)d_in[1];
    const float* W_ih  = (const float*)d_in[6];
    const float* W_hh  = (const float*)d_in[7];
    const float* b_ih  = (const float*)d_in[8];
    const float* b_hh  = (const float*)d_in[9];
    const float* W_reg = (const float*)d_in[10];
    const float* b_reg = (const float*)d_in[11];
    const float* W_out = (const float*)d_in[14];
    const float* b_out = (const float*)d_in[15];
    float* out = (float*)d_out;
    float* ws  = (float*)d_ws;

    hipMemsetAsync(ws, 0, T_ * sizeof(float), stream);
    pre_kernel<<<T_ * 8, 256, 0, stream>>>(masks, ws, out);
    brits_main<<<B_ / BT, 256, 0, stream>>>(x_t, masks, W_ih, W_hh, b_ih, b_hh,
                                            W_reg, b_reg, W_out, b_out, ws, out);
}

// Round 4
// 136.037 us; speedup vs baseline: 5.3078x; 1.0862x over previous
//
#include <hip/hip_runtime.h>
#include <stdint.h>

#define B_    4096
#define T_    48
#define D_    35
#define H_    64
#define KROW  168           // LDS A-row stride (elements); MFMA K extent = 160
#define BT    8             // batch rows per block
#define ROWEL (T_ * D_)     // 1680 elements per batch row
#define STASH_N (BT * ROWEL) // 13440 packed u32

typedef float f32x4 __attribute__((ext_vector_type(4)));
typedef short bf16x8 __attribute__((ext_vector_type(8)));

__device__ __forceinline__ float sigm(float z)  { return 1.0f / (1.0f + __expf(-z)); }
__device__ __forceinline__ float tanh_(float z) { return 2.0f / (1.0f + __expf(-2.0f * z)) - 1.0f; }
__device__ __forceinline__ uint32_t fbits(float x) { union { float f; uint32_t u; } v; v.f = x; return v.u; }
__device__ __forceinline__ float bitsf(uint32_t u) { union { uint32_t u; float f; } v; v.u = u; return v.f; }
__device__ __forceinline__ unsigned short f2bf_rne(float x) {
    uint32_t u = fbits(x);
    return (unsigned short)((u + 0x7fffu + ((u >> 16) & 1u)) >> 16);
}

// K-axis layout (A tile and weight fragments):
//   k 0..34 = x_c -> W_ih[:,0:35] ; k 35..69 = m -> W_ih[:,35:70]
//   k 70..71 = 0  ; k 72..135 = h -> W_hh   ; k 136..159 = 0

__global__ __launch_bounds__(256, 2)
void brits_main(const float* __restrict__ x_t, const float* __restrict__ masks,
                const float* __restrict__ W_ih, const float* __restrict__ W_hh,
                const float* __restrict__ b_ih, const float* __restrict__ b_hh,
                const float* __restrict__ W_reg, const float* __restrict__ b_reg,
                const float* __restrict__ W_out, const float* __restrict__ b_out,
                float* __restrict__ ws, float* __restrict__ out)
{
    __shared__ __align__(16) uint32_t stash[STASH_N];       // [r][t][d]: lo16=bf16(m*x) (later xc), hi16=bf16(m)
    __shared__ __align__(16) unsigned short Abuf[2][16 * KROW];
    __shared__ float lsum[T_][3][2];                        // per-t per-wave (num, den)
    __shared__ float wout[65];

    const int tid    = threadIdx.x;
    const int lane   = tid & 63;
    const int w      = tid >> 6;      // wave 0..3
    const int g      = lane >> 4;     // k-group / C row-group
    const int cc     = lane & 15;
    const int batch0 = blockIdx.x * BT;
    const int u      = w * 16 + cc;   // hidden unit / output column

    for (int i = tid; i < 2 * 16 * KROW; i += 256) ((unsigned short*)Abuf)[i] = 0;
    if (tid < 65) wout[tid] = (tid < 64) ? W_out[tid] : b_out[0];

    // ---- bulk load: pack m*x | m into LDS stash (only global reads of x/masks) ----
    for (int i = tid; i < STASH_N / 4; i += 256) {
        const int r = i / 420;                 // 420 float4 per row
        const int o = (i - r * 420) * 4;       // element offset within row
        const float4 xv = *(const float4*)(x_t   + (size_t)(batch0 + r) * ROWEL + o);
        const float4 mv = *(const float4*)(masks + (size_t)(batch0 + r) * ROWEL + o);
        uint32_t pk[4];
        #pragma unroll
        for (int k2 = 0; k2 < 4; ++k2) {
            const float m = (&mv.x)[k2];
            const float xm = m * (&xv.x)[k2];
            pk[k2] = (fbits(m) & 0xFFFF0000u) | (uint32_t)f2bf_rne(xm);
        }
        *(uint4*)&stash[r * ROWEL + o] = *(const uint4*)pk;
    }

    // ---- weights -> registers (constant across all 48 steps) ----
    bf16x8 Wf[4][5];
    #pragma unroll
    for (int nt = 0; nt < 4; ++nt) {
        const int n = nt * 64 + u;
        #pragma unroll
        for (int kk = 0; kk < 5; ++kk) {
            bf16x8 v;
            #pragma unroll
            for (int i = 0; i < 8; ++i) {
                const int k = kk * 32 + 8 * g + i;
                float f = 0.f;
                if (k < 70)                  f = W_ih[n * 70 + k];
                else if (k >= 72 && k < 136) f = W_hh[n * 64 + (k - 72)];
                v[i] = (short)f2bf_rne(f);
            }
            Wf[nt][kk] = v;
        }
    }
    bf16x8 Wr[2];
    #pragma unroll
    for (int kk = 0; kk < 2; ++kk) {
        bf16x8 v;
        #pragma unroll
        for (int i = 0; i < 8; ++i) {
            const int k = kk * 32 + 8 * g + i;
            float f = (w < 3 && u < 35) ? W_reg[u * 64 + k] : 0.f;
            v[i] = (short)f2bf_rne(f);
        }
        Wr[kk] = v;
    }
    const float brg = (w < 3 && u < 35) ? b_reg[u] : 0.f;
    const float bi  = b_ih[u]       + b_hh[u];
    const float bf_ = b_ih[64 + u]  + b_hh[64 + u];
    const float bg  = b_ih[128 + u] + b_hh[128 + u];
    const float bo  = b_ih[192 + u] + b_hh[192 + u];
    __syncthreads();

    float c_reg[4] = {0.f, 0.f, 0.f, 0.f};
    const bool pl = (w < 3) && (u < 35) && (g < 2);  // epilogue lanes (rows 0..7)

    int soff = 0;   // t * D_
    for (int t = 0; t < T_; ++t) {
        unsigned short* A  = Abuf[t & 1];
        unsigned short* An = Abuf[(t + 1) & 1];

        // ---- P1: x_hat = h @ W_reg^T + b_reg; epilogue all in LDS ----
        if (w < 3) {
            f32x4 acc = {0.f, 0.f, 0.f, 0.f};
            #pragma unroll
            for (int kk = 0; kk < 2; ++kk) {
                bf16x8 a = *(const bf16x8*)&A[cc * KROW + 72 + kk * 32 + 8 * g];
                acc = __builtin_amdgcn_mfma_f32_16x16x32_bf16(a, Wr[kk], acc, 0, 0, 0);
            }
            float lnum = 0.f, lden = 0.f;
            if (pl) {
                #pragma unroll
                for (int j = 0; j < 4; ++j) {
                    const int r   = 4 * g + j;
                    const int si  = r * ROWEL + soff + u;
                    const uint32_t pm = stash[si];
                    const float m  = bitsf(pm & 0xFFFF0000u);
                    const float xm = bitsf(pm << 16);
                    const float xh = acc[j] + brg;
                    lnum += fabsf(fmaf(-m, xh, xm));       // |x - xh| * m
                    lden += m;
                    const float xc = fmaf(1.f - m, xh, xm);
                    const uint32_t xcb = fbits(xc) >> 16;  // trunc-to-bf16
                    A[r * KROW + u]      = (unsigned short)xcb;
                    A[r * KROW + 35 + u] = (unsigned short)(pm >> 16);
                    stash[si] = (pm & 0xFFFF0000u) | xcb;  // archive xc for final dump
                }
            }
            #pragma unroll
            for (int off = 1; off < 64; off <<= 1) {
                lnum += __shfl_xor(lnum, off, 64);
                lden += __shfl_xor(lden, off, 64);
            }
            if (lane == 0) { lsum[t][w][0] = lnum; lsum[t][w][1] = lden; }
        }
        __syncthreads();

        // ---- P2: gates = A @ Wcomb^T (weights in VGPRs) ----
        f32x4 ai = {0,0,0,0}, af = {0,0,0,0}, ag = {0,0,0,0}, ao = {0,0,0,0};
        #pragma unroll
        for (int kk = 0; kk < 5; ++kk) {
            bf16x8 a = *(const bf16x8*)&A[cc * KROW + kk * 32 + 8 * g];
            ai = __builtin_amdgcn_mfma_f32_16x16x32_bf16(a, Wf[0][kk], ai, 0, 0, 0);
            af = __builtin_amdgcn_mfma_f32_16x16x32_bf16(a, Wf[1][kk], af, 0, 0, 0);
            ag = __builtin_amdgcn_mfma_f32_16x16x32_bf16(a, Wf[2][kk], ag, 0, 0, 0);
            ao = __builtin_amdgcn_mfma_f32_16x16x32_bf16(a, Wf[3][kk], ao, 0, 0, 0);
        }

        // ---- P3: cell update, write new h ----
        if (g < 2) {
            #pragma unroll
            for (int j = 0; j < 4; ++j) {
                float iv = sigm (ai[j] + bi);
                float fv = sigm (af[j] + bf_);
                float gv = tanh_(ag[j] + bg);
                float ov = sigm (ao[j] + bo);
                float cn = fv * c_reg[j] + iv * gv;
                c_reg[j] = cn;
                const float hn = ov * tanh_(cn);
                An[(4 * g + j) * KROW + 72 + u] = (unsigned short)(fbits(hn) >> 16);
            }
        }
        __syncthreads();
        soff += D_;
    }

    // ---- per-t loss partials -> spread atomics (once per block) ----
    if (tid < 96) {
        const int t = tid >> 1, k = tid & 1;
        const float v = lsum[t][0][k] + lsum[t][1][k] + lsum[t][2][k];
        atomicAdd(&ws[(k * T_ + t) * 8 + (blockIdx.x & 7)], v);
    }

    // ---- y_h = sigmoid(h_final @ W_out^T + b_out); final h in Abuf[0] ----
    if (w == 0 && cc < BT) {
        float p = 0.f;
        #pragma unroll
        for (int k = 0; k < 16; ++k)
            p += bitsf(((uint32_t)Abuf[0][cc * KROW + 72 + 16 * g + k]) << 16) * wout[16 * g + k];
        p += __shfl_xor(p, 16, 64);
        p += __shfl_xor(p, 32, 64);
        if (lane < 16) out[1 + batch0 + cc] = sigm(p + wout[64]);
    }

    // ---- bulk dump imputations (xc archived in stash lo16) ----
    for (int i = tid; i < STASH_N; i += 256) {
        const int r = i / ROWEL;
        const int o = i - r * ROWEL;
        out[1 + B_ + (size_t)(batch0 + r) * ROWEL + o] = bitsf(stash[i] << 16);
    }
}

// loss = (1/T) * sum_t num[t] / (den[t] + 1e-5); slots spread 8-way
__global__ void post_kernel(const float* __restrict__ ws, float* __restrict__ out)
{
    const int t = threadIdx.x;  // 64 threads
    float v = 0.f;
    if (t < T_) {
        float num = 0.f, den = 0.f;
        #pragma unroll
        for (int s = 0; s < 8; ++s) {
            num += ws[t * 8 + s];
            den += ws[(T_ + t) * 8 + s];
        }
        v = num / (den + 1e-5f);
    }
    #pragma unroll
    for (int off = 1; off < 64; off <<= 1) v += __shfl_xor(v, off, 64);
    if (t == 0) out[0] = v * (1.0f / T_);
}

extern "C" void kernel_launch(void* const* d_in, const int* in_sizes, int n_in,
                              void* d_out, int out_size, void* d_ws, size_t ws_size,
                              hipStream_t stream) {
    const float* x_t   = (const float*)d_in[0];
    const float* masks = (const float*)d_in[1];
    const float* W_ih  = (const float*)d_in[6];
    const float* W_hh  = (const float*)d_in[7];
    const float* b_ih  = (const float*)d_in[8];
    const float* b_hh  = (const float*)d_in[9];
    const float* W_reg = (const float*)d_in[10];
    const float* b_reg = (const float*)d_in[11];
    const float* W_out = (const float*)d_in[14];
    const float* b_out = (const float*)d_in[15];
    float* out = (float*)d_out;
    float* ws  = (float*)d_ws;

    hipMemsetAsync(ws, 0, 2 * T_ * 8 * sizeof(float), stream);
    brits_main<<<B_ / BT, 256, 0, stream>>>(x_t, masks, W_ih, W_hh, b_ih, b_hh,
                                            W_reg, b_reg, W_out, b_out, ws, out);
    post_kernel<<<1, 64, 0, stream>>>(ws, out);
}